// Round 15
// baseline (87.780 us; speedup 1.0000x reference)
//
#include <hip/hip_runtime.h>
#include <hip/hip_bf16.h>
#include <math.h>

// Problem constants (fixed by the reference)
#define NPIX 256
#define HALF 128
#define NVIS 50000
#define TWO_PI_F 6.28318530717958647692f

// vis kernel geometry: 4 waves per block, 16 k's per wave (64 k/block)
#define VBLK 256
#define KPB  64
#define NBLK_VIS ((NVIS + KPB - 1) / KPB)   // 782 (covers 50048; tail guarded)

typedef __attribute__((ext_vector_type(8))) short short8;
typedef __attribute__((ext_vector_type(4))) float float4v;

__device__ __forceinline__ float cell_rad_f() {
    // match reference: jnp.float32(0.005) * np.float32(pi/180/3600)
    const float arcsec = (float)(M_PI / 180.0 / 3600.0);
    return 0.005f * arcsec;
}

__device__ __forceinline__ unsigned pack_bf2(float lo, float hi) {
    // 2x f32 -> packed bf16 pair (v_cvt_pk_bf16_f32)
    __hip_bfloat162 h = __float22bfloat162_rn(make_float2(lo, hi));
    return *reinterpret_cast<unsigned*>(&h);
}

// ---------------------------------------------------------------------------
// Prep: softplus + 3x3 Hann conv (math verified R3/R6/R8), emitted as bf16 in
// 16x16x32 A-fragment order (A = image, M=16 y, K=32 x):
//   element (lane, e) = img[y = yt*16 + (lane&15)][x = step*32 + (lane>>4)*8 + e]
//   wimg[((yt*8 + step)*64 + lane)*8 + e],  yt in [0,16), step in [0,8)
// Grid: 32 blocks = (by 0..15: 16-row strip) x (xh 0..1: 128-col half).
// ---------------------------------------------------------------------------
#define SPR 18
#define SPC 130
__global__ __launch_bounds__(256) void prep_kernel(const float* __restrict__ base,
                                                   unsigned short* __restrict__ wimg) {
    __shared__ float sp[SPR][SPC];
    const int by = blockIdx.x >> 1, xh = blockIdx.x & 1;
    const int y0 = by * 16, x0 = xh * 128;
    const int tid = threadIdx.x;

    for (int idx = tid; idx < SPR * SPC; idx += 256) {
        int r = idx / SPC, c = idx - r * SPC;
        int y = y0 - 1 + r, x = x0 - 1 + c;
        float v = 0.f;
        if ((unsigned)y < NPIX && (unsigned)x < NPIX)
            v = log1pf(expf(base[y * NPIX + x]));
        sp[r][c] = v;
    }
    __syncthreads();

    // one conv octet per thread: yl = tid>>4 (row), oc = tid&15 (8-px column run)
    {
        int yl = tid >> 4, oc = tid & 15;
        union { unsigned short u[8]; uint4 v; } pk;
        #pragma unroll
        for (int e = 0; e < 8; ++e) {
            int cl = oc * 8 + e;     // sp col of conv-center-minus-1
            float top = sp[yl    ][cl] + 2.f * sp[yl    ][cl + 1] + sp[yl    ][cl + 2];
            float mid = sp[yl + 1][cl] + 2.f * sp[yl + 1][cl + 1] + sp[yl + 1][cl + 2];
            float bot = sp[yl + 2][cl] + 2.f * sp[yl + 2][cl + 1] + sp[yl + 2][cl + 2];
            float cv  = 0.0625f * (top + 2.f * mid + bot);
            __hip_bfloat16 h = __float2bfloat16(cv);
            pk.u[e] = *reinterpret_cast<unsigned short*>(&h);
        }
        // global octet: y = by*16 + yl, x0g = xh*128 + oc*8
        int step = xh * 4 + (oc >> 2);       // (x0g)>>5
        int hi   = oc & 3;                   // ((x0g)>>3)&3
        size_t off = (((size_t)by * 8 + step) * 64 + hi * 16 + yl) * 8;
        *(uint4*)(wimg + off) = pk.v;
    }
}

// ---------------------------------------------------------------------------
// Vis: 16x16x32 bf16 MFMA NUDFT. A = image (from global, L1/L2-hit), B = phase
// (registers, 64 VGPR). Mappings HW-verified by the R8 pass:
//   A row = lane&15 (y), K-elem = (lane>>4)*8+e (x)
//   B col = lane&15 (k), K-elem = (lane>>4)*8+e (x)
//   C/D  col = lane&15 (k), row = (lane>>4)*4+reg (y)   [m89]
// Register budget (R8-R13 lesson: spill = latency wall): B 64 + A 8x4=32 +
// acc 8 + epilogue ~10 + misc ~35 = ~150 <= 170 cap (launch_bounds(256,3)).
// 4 waves/block all stream the SAME wimg sequence; a per-yt __syncthreads
// keeps them within one 8KB tile so L1 serves 3/4 of reads: L2 traffic
// 400 MB (R14) -> 100 MB. No LDS. Epilogue y-phase via rotation recurrence.
// Output planar f32 [re-plane][im-plane] (verified R6).
// ---------------------------------------------------------------------------
__global__ __launch_bounds__(VBLK, 3) void vis_mfma(const float* __restrict__ uu,
                                                    const float* __restrict__ vv,
                                                    const unsigned short* __restrict__ wimg,
                                                    float* __restrict__ out) {
    const int tid  = threadIdx.x;
    const int wid  = tid >> 6, lane = tid & 63;
    const int lo = lane & 15, hi = lane >> 4;
    const int k0 = blockIdx.x * KPB + wid * 16;
    const int ko = k0 + lo;                      // this lane's k (unclamped)
    const int ka = (ko < NVIS) ? ko : (NVIS - 1);

    const float cell = cell_rad_f();
    const float sc   = TWO_PI_F * 1e3f * cell;
    const float del  = sc * uu[ka];
    const float eps  = sc * vv[ka];

    // --- x-rotations: rot1x = exp(-i*del); rot32x = rot1x^32 (5 squarings) ---
    float cd, sd; sincosf(del, &sd, &cd);
    const float x1r = cd, x1i = -sd;
    float xr = x1r, xi = x1i;
    #pragma unroll
    for (int q = 0; q < 5; ++q) {                // -> rot32x
        float nr = fmaf(xr, xr, -xi * xi);
        float ni = 2.f * xr * xi;
        xr = nr; xi = ni;
    }
    const float x32r = xr, x32i = xi;

    // --- B phase fragments: x = step*32 + hi*8 + e, value exp(-i*del*(x-128)) ---
    float th0 = del * (float)(hi * 8 - HALF);
    float s0, c0; sincosf(th0, &s0, &c0);
    float bar = c0, bai = -s0;                   // base at e=0 of step 0

    union BF { short8 v; unsigned u[4]; };
    BF Bre[8], Bim[8];
    #pragma unroll
    for (int step = 0; step < 8; ++step) {
        float ar = bar, ai = bai;
        #pragma unroll
        for (int ep = 0; ep < 4; ++ep) {
            float ar1 = fmaf(ar, x1r, -ai * x1i);    // *= rot1x
            float ai1 = fmaf(ai, x1r,  ar * x1i);
            Bre[step].u[ep] = pack_bf2(ar, ar1);
            Bim[step].u[ep] = pack_bf2(ai, ai1);
            ar = fmaf(ar1, x1r, -ai1 * x1i);
            ai = fmaf(ai1, x1r,  ar1 * x1i);
        }
        float nbr = fmaf(bar, x32r, -bai * x32i);    // base *= rot32x
        float nbi = fmaf(bai, x32r,  bar * x32i);
        bar = nbr; bai = nbi;
    }

    // --- y-phase state: b[r] = exp(-i*eps*(y-128)), y = yt*16 + hi*4 + r ---
    float ce, se; sincosf(eps, &se, &ce);
    const float y1r = ce, y1i = -se;             // rot1y
    float yr = y1r, yi = y1i;
    #pragma unroll
    for (int q = 0; q < 4; ++q) {                // -> rot16y
        float nr = fmaf(yr, yr, -yi * yi);
        float ni = 2.f * yr * yi;
        yr = nr; yi = ni;
    }
    const float y16r = yr, y16i = yi;

    float br[4], bi[4];
    {
        float w0 = eps * (float)(hi * 4 - HALF);
        float sw, cw; sincosf(w0, &sw, &cw);
        br[0] = cw; bi[0] = -sw;
        #pragma unroll
        for (int r = 1; r < 4; ++r) {
            br[r] = fmaf(br[r-1], y1r, -bi[r-1] * y1i);
            bi[r] = fmaf(bi[r-1], y1r,  br[r-1] * y1i);
        }
    }

    float visr = 0.f, visi = 0.f;
    const short8* __restrict__ Afrag = (const short8*)wimg;  // idx = (yt*8+step)*64+lane

    #pragma unroll 1
    for (int yt = 0; yt < 16; ++yt) {
        // keep the 4 waves of this block in step so L1 serves the shared stream
        __syncthreads();

        short8 A[8];
        #pragma unroll
        for (int j = 0; j < 8; ++j) A[j] = Afrag[((yt * 8 + j) * 64) + lane];

        float4v accR = {0.f, 0.f, 0.f, 0.f}, accI = {0.f, 0.f, 0.f, 0.f};
        #pragma unroll
        for (int j = 0; j < 8; ++j) {
            accR = __builtin_amdgcn_mfma_f32_16x16x32_bf16(A[j], Bre[j].v, accR, 0, 0, 0);
            accI = __builtin_amdgcn_mfma_f32_16x16x32_bf16(A[j], Bim[j].v, accI, 0, 0, 0);
        }

        // vis += T*b per r; then b[r] *= rot16y
        #pragma unroll
        for (int r = 0; r < 4; ++r) {
            visr = fmaf(accR[r], br[r], visr); visr = fmaf(-accI[r], bi[r], visr);
            visi = fmaf(accI[r], br[r], visi); visi = fmaf( accR[r], bi[r], visi);
            float nr = fmaf(br[r], y16r, -bi[r] * y16i);
            float ni = fmaf(bi[r], y16r,  br[r] * y16i);
            br[r] = nr; bi[r] = ni;
        }
    }

    // reduce over hi-groups (lanes lane^16, lane^32 span the 4 y-row groups)
    visr += __shfl_xor(visr, 16); visr += __shfl_xor(visr, 32);
    visi += __shfl_xor(visi, 16); visi += __shfl_xor(visi, 32);

    if (hi == 0 && ko < NVIS) {
        const float c2 = cell * cell;
        out[ko]        = visr * c2;   // real plane
        out[NVIS + ko] = visi * c2;   // imag plane
    }
}

extern "C" void kernel_launch(void* const* d_in, const int* in_sizes, int n_in,
                              void* d_out, int out_size, void* d_ws, size_t ws_size,
                              hipStream_t stream) {
    const float* base = (const float*)d_in[0];   // (1,256,256) f32
    const float* uu   = (const float*)d_in[1];   // (50000,) f32
    const float* vv   = (const float*)d_in[2];   // (50000,) f32
    (void)in_sizes; (void)n_in; (void)out_size; (void)ws_size;

    unsigned short* wimg = (unsigned short*)d_ws;    // 128 KB fragment-ordered bf16 image

    prep_kernel<<<32, 256, 0, stream>>>(base, wimg);
    vis_mfma<<<NBLK_VIS, VBLK, 0, stream>>>(uu, vv, wimg, (float*)d_out);
}

// Round 16
// 80.701 us; speedup vs baseline: 1.0877x; 1.0877x over previous
//
#include <hip/hip_runtime.h>
#include <hip/hip_bf16.h>
#include <math.h>

// Problem constants (fixed by the reference)
#define NPIX 256
#define HALF 128
#define NVIS 50000
#define TWO_PI_F 6.28318530717958647692f

// vis kernel geometry: 1 wave per block, 16 k's per wave (50000 = 3125 * 16)
#define VBLK 64
#define KPB  16
#define NBLK_VIS (NVIS / KPB)   // 3125, exact

typedef __attribute__((ext_vector_type(8))) short short8;
typedef __attribute__((ext_vector_type(4))) float float4v;

__device__ __forceinline__ float cell_rad_f() {
    // match reference: jnp.float32(0.005) * np.float32(pi/180/3600)
    const float arcsec = (float)(M_PI / 180.0 / 3600.0);
    return 0.005f * arcsec;
}

__device__ __forceinline__ unsigned pack_bf2(float lo, float hi) {
    // 2x f32 -> packed bf16 pair (v_cvt_pk_bf16_f32)
    __hip_bfloat162 h = __float22bfloat162_rn(make_float2(lo, hi));
    return *reinterpret_cast<unsigned*>(&h);
}

// ---------------------------------------------------------------------------
// Prep: softplus + 3x3 Hann conv (math verified R3/R6/R8), emitted as bf16 in
// 16x16x32 A-fragment order (A = image, M=16 y, K=32 x):
//   element (lane, e) = img[y = yt*16 + (lane&15)][x = step*32 + (lane>>4)*8 + e]
//   wimg[((yt*8 + step)*64 + lane)*8 + e],  yt in [0,16), step in [0,8)
// Grid: 32 blocks = (by 0..15: 16-row strip) x (xh 0..1: 128-col half).
// ---------------------------------------------------------------------------
#define SPR 18
#define SPC 130
__global__ __launch_bounds__(256) void prep_kernel(const float* __restrict__ base,
                                                   unsigned short* __restrict__ wimg) {
    __shared__ float sp[SPR][SPC];
    const int by = blockIdx.x >> 1, xh = blockIdx.x & 1;
    const int y0 = by * 16, x0 = xh * 128;
    const int tid = threadIdx.x;

    for (int idx = tid; idx < SPR * SPC; idx += 256) {
        int r = idx / SPC, c = idx - r * SPC;
        int y = y0 - 1 + r, x = x0 - 1 + c;
        float v = 0.f;
        if ((unsigned)y < NPIX && (unsigned)x < NPIX)
            v = log1pf(expf(base[y * NPIX + x]));
        sp[r][c] = v;
    }
    __syncthreads();

    // one conv octet per thread: yl = tid>>4 (row), oc = tid&15 (8-px column run)
    {
        int yl = tid >> 4, oc = tid & 15;
        union { unsigned short u[8]; uint4 v; } pk;
        #pragma unroll
        for (int e = 0; e < 8; ++e) {
            int cl = oc * 8 + e;     // sp col of conv-center-minus-1
            float top = sp[yl    ][cl] + 2.f * sp[yl    ][cl + 1] + sp[yl    ][cl + 2];
            float mid = sp[yl + 1][cl] + 2.f * sp[yl + 1][cl + 1] + sp[yl + 1][cl + 2];
            float bot = sp[yl + 2][cl] + 2.f * sp[yl + 2][cl + 1] + sp[yl + 2][cl + 2];
            float cv  = 0.0625f * (top + 2.f * mid + bot);
            __hip_bfloat16 h = __float2bfloat16(cv);
            pk.u[e] = *reinterpret_cast<unsigned short*>(&h);
        }
        // global octet: y = by*16 + yl, x0g = xh*128 + oc*8
        int step = xh * 4 + (oc >> 2);       // (x0g)>>5
        int hi   = oc & 3;                   // ((x0g)>>3)&3
        size_t off = (((size_t)by * 8 + step) * 64 + hi * 16 + yl) * 8;
        *(uint4*)(wimg + off) = pk.v;
    }
}

// ---------------------------------------------------------------------------
// Vis: 16x16x32 bf16 MFMA NUDFT. A = image (from global, L2-hit), B = phase
// (registers, 64 VGPR). Mappings HW-verified by the R8 pass:
//   A row = lane&15 (y), K-elem = (lane>>4)*8+e (x)
//   B col = lane&15 (k), K-elem = (lane>>4)*8+e (x)
//   C/D  col = lane&15 (k), row = (lane>>4)*4+reg (y)   [m89]
// R16: SOFTWARE-PIPELINED yt loop (the R14/R15 structure serialized
// {load -> stall -> MFMA} per tile). Fully unrolled, 2-deep A double-buffer:
// yt+1's 8 loads issue BEFORE yt's MFMA cluster, hiding L2 latency under the
// MFMA chain + epilogue VALU. All indices static (rule #20). No barriers.
// Register budget: B 64 + Abuf 64 + acc 8 + y-state 12 + misc ~35 = ~185
// <= 256 cap (launch_bounds(64,2), 2 waves/SIMD co-resident).
// Output planar f32 [re-plane][im-plane] (verified R6).
// ---------------------------------------------------------------------------
__global__ __launch_bounds__(VBLK, 2) void vis_mfma(const float* __restrict__ uu,
                                                    const float* __restrict__ vv,
                                                    const unsigned short* __restrict__ wimg,
                                                    float* __restrict__ out) {
    const int lane = threadIdx.x & 63;
    const int lo = lane & 15, hi = lane >> 4;
    const int k0 = blockIdx.x * KPB;
    const int ka = k0 + lo;                      // this lane's k (B col & D col)

    const float cell = cell_rad_f();
    const float sc   = TWO_PI_F * 1e3f * cell;
    const float del  = sc * uu[ka];
    const float eps  = sc * vv[ka];

    // --- x-rotations: rot1x = exp(-i*del); rot32x = rot1x^32 (5 squarings) ---
    float cd, sd; sincosf(del, &sd, &cd);
    const float x1r = cd, x1i = -sd;
    float xr = x1r, xi = x1i;
    #pragma unroll
    for (int q = 0; q < 5; ++q) {                // -> rot32x
        float nr = fmaf(xr, xr, -xi * xi);
        float ni = 2.f * xr * xi;
        xr = nr; xi = ni;
    }
    const float x32r = xr, x32i = xi;

    // --- B phase fragments: x = step*32 + hi*8 + e, value exp(-i*del*(x-128)) ---
    float th0 = del * (float)(hi * 8 - HALF);
    float s0, c0; sincosf(th0, &s0, &c0);
    float bar = c0, bai = -s0;                   // base at e=0 of step 0

    union BF { short8 v; unsigned u[4]; };
    BF Bre[8], Bim[8];
    #pragma unroll
    for (int step = 0; step < 8; ++step) {
        float ar = bar, ai = bai;
        #pragma unroll
        for (int ep = 0; ep < 4; ++ep) {
            float ar1 = fmaf(ar, x1r, -ai * x1i);    // *= rot1x
            float ai1 = fmaf(ai, x1r,  ar * x1i);
            Bre[step].u[ep] = pack_bf2(ar, ar1);
            Bim[step].u[ep] = pack_bf2(ai, ai1);
            ar = fmaf(ar1, x1r, -ai1 * x1i);
            ai = fmaf(ai1, x1r,  ar1 * x1i);
        }
        float nbr = fmaf(bar, x32r, -bai * x32i);    // base *= rot32x
        float nbi = fmaf(bai, x32r,  bar * x32i);
        bar = nbr; bai = nbi;
    }

    // --- y-phase state: b[r] = exp(-i*eps*(y-128)), y = yt*16 + hi*4 + r ---
    float ce, se; sincosf(eps, &se, &ce);
    const float y1r = ce, y1i = -se;             // rot1y
    float yr = y1r, yi = y1i;
    #pragma unroll
    for (int q = 0; q < 4; ++q) {                // -> rot16y
        float nr = fmaf(yr, yr, -yi * yi);
        float ni = 2.f * yr * yi;
        yr = nr; yi = ni;
    }
    const float y16r = yr, y16i = yi;

    float br[4], bi[4];
    {
        float w0 = eps * (float)(hi * 4 - HALF);
        float sw, cw; sincosf(w0, &sw, &cw);
        br[0] = cw; bi[0] = -sw;
        #pragma unroll
        for (int r = 1; r < 4; ++r) {
            br[r] = fmaf(br[r-1], y1r, -bi[r-1] * y1i);
            bi[r] = fmaf(bi[r-1], y1r,  br[r-1] * y1i);
        }
    }

    float visr = 0.f, visi = 0.f;
    const short8* __restrict__ Afrag = (const short8*)wimg;  // idx = (yt*8+step)*64+lane

    // --- pipelined y-tile loop: prefetch yt+1 before computing yt ---
    short8 Abuf[2][8];
    #pragma unroll
    for (int j = 0; j < 8; ++j) Abuf[0][j] = Afrag[(j * 64) + lane];

    #pragma unroll
    for (int yt = 0; yt < 16; ++yt) {
        const int cur = yt & 1, nxt = cur ^ 1;   // static after full unroll

        if (yt < 15) {
            #pragma unroll
            for (int j = 0; j < 8; ++j)
                Abuf[nxt][j] = Afrag[(((yt + 1) * 8 + j) * 64) + lane];
        }

        float4v accR = {0.f, 0.f, 0.f, 0.f}, accI = {0.f, 0.f, 0.f, 0.f};
        #pragma unroll
        for (int j = 0; j < 8; ++j) {
            accR = __builtin_amdgcn_mfma_f32_16x16x32_bf16(Abuf[cur][j], Bre[j].v, accR, 0, 0, 0);
            accI = __builtin_amdgcn_mfma_f32_16x16x32_bf16(Abuf[cur][j], Bim[j].v, accI, 0, 0, 0);
        }

        // vis += T*b per r; then b[r] *= rot16y
        #pragma unroll
        for (int r = 0; r < 4; ++r) {
            visr = fmaf(accR[r], br[r], visr); visr = fmaf(-accI[r], bi[r], visr);
            visi = fmaf(accI[r], br[r], visi); visi = fmaf( accR[r], bi[r], visi);
            float nr = fmaf(br[r], y16r, -bi[r] * y16i);
            float ni = fmaf(bi[r], y16r,  br[r] * y16i);
            br[r] = nr; bi[r] = ni;
        }
    }

    // reduce over hi-groups (lanes lane^16, lane^32 span the 4 y-row groups)
    visr += __shfl_xor(visr, 16); visr += __shfl_xor(visr, 32);
    visi += __shfl_xor(visi, 16); visi += __shfl_xor(visi, 32);

    if (hi == 0) {
        const float c2 = cell * cell;
        out[ka]        = visr * c2;   // real plane
        out[NVIS + ka] = visi * c2;   // imag plane
    }
}

extern "C" void kernel_launch(void* const* d_in, const int* in_sizes, int n_in,
                              void* d_out, int out_size, void* d_ws, size_t ws_size,
                              hipStream_t stream) {
    const float* base = (const float*)d_in[0];   // (1,256,256) f32
    const float* uu   = (const float*)d_in[1];   // (50000,) f32
    const float* vv   = (const float*)d_in[2];   // (50000,) f32
    (void)in_sizes; (void)n_in; (void)out_size; (void)ws_size;

    unsigned short* wimg = (unsigned short*)d_ws;    // 128 KB fragment-ordered bf16 image

    prep_kernel<<<32, 256, 0, stream>>>(base, wimg);
    vis_mfma<<<NBLK_VIS, VBLK, 0, stream>>>(uu, vv, wimg, (float*)d_out);
}